// Round 1
// baseline (31355.481 us; speedup 1.0000x reference)
//
#include <hip/hip_runtime.h>

// ---------------------------------------------------------------------------
// VanillaRNN on MI355X (gfx950)
// B=128, S=1024, H=1024, E=512, V=256
//
// Plan:
//  1. prep:   bf16-convert W_hh, W_ho; h_all[:,0,:] = hidden; zero barriers
//  2. proj:   proj[v][h] = b_ih[h] + b_hh[h] + dot(emb[v,:], W_ih[h,:])  (fp32)
//  3. rnn_seq: persistent kernel, 8 groups x 32 WGs (group = wg&7 -> XCD),
//             each group owns 16 batch rows; W_hh slice lives in VGPRs;
//             per-step group barrier via agent-scope atomics.
//             h_t stored as bf16 into h_all[B][S+1][H].
//  4. out_gemm: out[b,s,v] = dot(h_all[b,s+1,:], W_ho[v,:]) + b_ho[v]  (MFMA)
//  5. hfinal: d_out tail = fp32(h_all[:,S,:])
// ---------------------------------------------------------------------------

typedef __attribute__((ext_vector_type(8))) short bhalf8;   // 8 bf16 (4 VGPR)
typedef __attribute__((ext_vector_type(4))) float floatx4;  // 4 f32

typedef unsigned short u16;
typedef unsigned int u32;

#define B_  128
#define S_  1024
#define H_  1024
#define E_  512
#define V_  256

// ws layout (bytes)
#define H_ALL_BYTES   (268697600ull)            // 128*1025*1024*2
#define WHH_OFF       (268697600ull)
#define WHO_OFF       (WHH_OFF + 2097152ull)    // 1024*1024*2
#define PROJ_OFF      (WHO_OFF + 524288ull)     // 256*1024*2
#define CNT_OFF       (PROJ_OFF + 1048576ull)   // 256*1024*4

__device__ inline u16 f2bf(float f) {
    u32 u = __builtin_bit_cast(u32, f);
    u32 lsb = (u >> 16) & 1u;
    u += 0x7fffu + lsb;
    return (u16)(u >> 16);
}
__device__ inline float bf2f(u16 h) {
    u32 u = ((u32)h) << 16;
    return __builtin_bit_cast(float, u);
}
__device__ inline bhalf8 ld8(const u16* p) {
    return *(const bhalf8*)p;
}

// ---------------------------------------------------------------------------
// 1. prep
// ---------------------------------------------------------------------------
__global__ __launch_bounds__(256) void prep_kernel(
    const float* __restrict__ W_hh, const float* __restrict__ W_ho,
    const float* __restrict__ hidden,
    u16* __restrict__ Whh_bf, u16* __restrict__ Who_bf,
    u16* __restrict__ h_all, int* __restrict__ cnt)
{
    int i = blockIdx.x * 256 + threadIdx.x;
    if (i < 1048576) {
        Whh_bf[i] = f2bf(W_hh[i]);
    } else if (i < 1048576 + 262144) {
        int j = i - 1048576;
        Who_bf[j] = f2bf(W_ho[j]);
    } else if (i < 1048576 + 262144 + 131072) {
        int j = i - (1048576 + 262144);
        int b = j >> 10, k = j & 1023;
        h_all[(size_t)b * 1025 * 1024 + k] = f2bf(hidden[j]);   // t = 0 row
    } else if (i < 1048576 + 262144 + 131072 + 128) {
        cnt[i - (1048576 + 262144 + 131072)] = 0;
    }
}

// ---------------------------------------------------------------------------
// 2. proj table: proj[v][h] = b_ih[h] + b_hh[h] + sum_e emb[v][e]*W_ih[h][e]
// ---------------------------------------------------------------------------
__global__ __launch_bounds__(256) void proj_kernel(
    const float* __restrict__ emb, const float* __restrict__ W_ih,
    const float* __restrict__ b_ih, const float* __restrict__ b_hh,
    float* __restrict__ proj)
{
    __shared__ float er[E_];
    int v = blockIdx.x, tid = threadIdx.x;
    er[tid]       = emb[v * E_ + tid];
    er[tid + 256] = emb[v * E_ + 256 + tid];
    __syncthreads();
    const float4* x = (const float4*)er;
    #pragma unroll
    for (int j = 0; j < 4; ++j) {
        int hc = tid + j * 256;
        const float4* w = (const float4*)&W_ih[(size_t)hc * E_];
        float s = 0.f;
        #pragma unroll 8
        for (int e = 0; e < E_ / 4; ++e) {
            float4 ww = w[e]; float4 xx = x[e];
            s += ww.x * xx.x + ww.y * xx.y + ww.z * xx.z + ww.w * xx.w;
        }
        proj[v * H_ + hc] = s + b_ih[hc] + b_hh[hc];
    }
}

// ---------------------------------------------------------------------------
// 3. persistent sequential RNN kernel
//    grid = 256 WGs x 256 threads. group g = wg&7 (XCD-aligned), 32 WGs/group,
//    group owns batch rows [g*16, g*16+16). WG owns 32 h-columns. 4 waves
//    split K=1024 into 256-slices; LDS reduce; tanh; bf16 store; barrier.
// ---------------------------------------------------------------------------
__global__ __launch_bounds__(256) void rnn_seq(
    const int* __restrict__ seq, const float* __restrict__ proj,
    const u16* __restrict__ Whh, u16* __restrict__ h_all,
    int* __restrict__ cnt)
{
    const int wg = blockIdx.x;
    const int g = wg & 7;
    const int wslot = wg >> 3;          // 0..31 within group
    const int colbase = wslot * 32;
    const int tid = threadIdx.x;
    const int wave = tid >> 6;
    const int lane = tid & 63;
    const int l16 = lane & 15, lq = lane >> 4;
    const int kb = wave * 256;          // wave's K-slice base

    // W_hh slice resident in registers: 2 col-tiles x 8 k-steps
    bhalf8 bfrag[2][8];
    #pragma unroll
    for (int tt = 0; tt < 2; ++tt) {
        #pragma unroll
        for (int ks = 0; ks < 8; ++ks) {
            bfrag[tt][ks] = ld8(&Whh[(size_t)(colbase + tt * 16 + l16) * H_
                                     + kb + ks * 32 + lq * 8]);
        }
    }

    __shared__ float red[4][2][16][17];   // [wave][tile][row][col+pad]

    int* mycnt = &cnt[g * 16];
    const int b0 = g * 16;
    const size_t aRowBase = ((size_t)(b0 + l16) * 1025) * 1024;  // per-lane h row

    // reduce-phase fixed indices
    const int rr = tid & 15;            // batch row within group
    const int cp = tid >> 4;            // 0..15 -> col pair
    const int c0 = 2 * cp, c1 = c0 + 1;
    const size_t hOutBase = ((size_t)(b0 + rr) * 1025) * 1024 + colbase + c0;
    const int seqBase = (b0 + rr) * S_;

    for (int t = 0; t < S_; ++t) {
        // --- MFMA: z_partial[16 x 32] over this wave's K-slice ---
        const u16* hp = h_all + aRowBase + (size_t)t * 1024 + kb + lq * 8;
        floatx4 acc0 = {0.f, 0.f, 0.f, 0.f};
        floatx4 acc1 = {0.f, 0.f, 0.f, 0.f};
        #pragma unroll
        for (int ks = 0; ks < 8; ++ks) {
            bhalf8 a = ld8(hp + ks * 32);
            acc0 = __builtin_amdgcn_mfma_f32_16x16x32_bf16(a, bfrag[0][ks], acc0, 0, 0, 0);
            acc1 = __builtin_amdgcn_mfma_f32_16x16x32_bf16(a, bfrag[1][ks], acc1, 0, 0, 0);
        }
        __syncthreads();                 // prev-iter LDS reads complete
        #pragma unroll
        for (int j = 0; j < 4; ++j) {    // D layout: row=(lq*4+j), col=l16
            red[wave][0][lq * 4 + j][l16] = acc0[j];
            red[wave][1][lq * 4 + j][l16] = acc1[j];
        }
        __syncthreads();

        // --- reduce 4 waves + x_proj + tanh + bf16 store (2 cols/thread) ---
        int tok = seq[seqBase + t];
        float2 pj = *(const float2*)&proj[tok * H_ + colbase + c0];
        float z0 = red[0][c0 >> 4][rr][c0 & 15] + red[1][c0 >> 4][rr][c0 & 15]
                 + red[2][c0 >> 4][rr][c0 & 15] + red[3][c0 >> 4][rr][c0 & 15] + pj.x;
        float z1 = red[0][c1 >> 4][rr][c1 & 15] + red[1][c1 >> 4][rr][c1 & 15]
                 + red[2][c1 >> 4][rr][c1 & 15] + red[3][c1 >> 4][rr][c1 & 15] + pj.y;
        u32 pack = (u32)f2bf(tanhf(z0)) | ((u32)f2bf(tanhf(z1)) << 16);
        *(u32*)&h_all[hOutBase + (size_t)(t + 1) * 1024] = pack;

        // --- group barrier: syncthreads drains all waves' stores (vmcnt0),
        //     then leader publishes with agent-scope release ---
        __syncthreads();
        if (tid == 0)
            __hip_atomic_fetch_add(mycnt, 1, __ATOMIC_RELEASE, __HIP_MEMORY_SCOPE_AGENT);
        const int target = 32 * (t + 1);
        while (__hip_atomic_load(mycnt, __ATOMIC_ACQUIRE, __HIP_MEMORY_SCOPE_AGENT) < target) {}
        // no trailing sync needed: next iteration's first __syncthreads realigns
    }
}

// ---------------------------------------------------------------------------
// 4. output GEMM: out[b][s][v] = dot(h_all[b][s+1][:], W_ho[v][:]) + b_ho[v]
//    WG: one b, 64 s-rows; wave w -> v-block w*64 (4 v-tiles), 4 s-tiles.
// ---------------------------------------------------------------------------
__global__ __launch_bounds__(256) void out_gemm(
    const u16* __restrict__ h_all, const u16* __restrict__ Who,
    const float* __restrict__ b_ho, float* __restrict__ out)
{
    const int wg = blockIdx.x;          // 2048 = 128 b x 16 s-tiles
    const int b = wg >> 4;
    const int st = wg & 15;
    const int sbase = st * 64;
    const int tid = threadIdx.x;
    const int wave = tid >> 6;
    const int lane = tid & 63;
    const int l16 = lane & 15, lq = lane >> 4;
    const int vb = wave * 64;

    floatx4 acc[4][4] = {};             // [s-sub][v-sub]
    size_t arow[4];
    #pragma unroll
    for (int ss = 0; ss < 4; ++ss)
        arow[ss] = ((size_t)b * 1025 + sbase + ss * 16 + l16 + 1) * 1024;

    for (int ks = 0; ks < 32; ++ks) {
        const int k = ks * 32 + lq * 8;
        bhalf8 bb[4];
        #pragma unroll
        for (int vt = 0; vt < 4; ++vt)
            bb[vt] = ld8(&Who[(size_t)(vb + vt * 16 + l16) * H_ + k]);
        #pragma unroll
        for (int ss = 0; ss < 4; ++ss) {
            bhalf8 aa = ld8(&h_all[arow[ss] + k]);
            #pragma unroll
            for (int vt = 0; vt < 4; ++vt)
                acc[ss][vt] = __builtin_amdgcn_mfma_f32_16x16x32_bf16(aa, bb[vt], acc[ss][vt], 0, 0, 0);
        }
    }
    #pragma unroll
    for (int ss = 0; ss < 4; ++ss) {
        #pragma unroll
        for (int vt = 0; vt < 4; ++vt) {
            int v = vb + vt * 16 + l16;
            float bias = b_ho[v];
            #pragma unroll
            for (int j = 0; j < 4; ++j) {
                int s = sbase + ss * 16 + lq * 4 + j;
                out[((size_t)b << 18) + (size_t)s * V_ + v] = acc[ss][vt][j] + bias;
            }
        }
    }
}

// ---------------------------------------------------------------------------
// 5. h_final
// ---------------------------------------------------------------------------
__global__ __launch_bounds__(256) void hfinal(const u16* __restrict__ h_all,
                                              float* __restrict__ out)
{
    int i = blockIdx.x * 256 + threadIdx.x;   // 131072
    int b = i >> 10, k = i & 1023;
    out[33554432 + i] = bf2f(h_all[((size_t)b * 1025 + 1024) * 1024 + k]);
}

// ---------------------------------------------------------------------------
extern "C" void kernel_launch(void* const* d_in, const int* in_sizes, int n_in,
                              void* d_out, int out_size, void* d_ws, size_t ws_size,
                              hipStream_t stream) {
    const int*   seq    = (const int*)  d_in[0];
    const float* hidden = (const float*)d_in[1];
    const float* emb    = (const float*)d_in[2];
    const float* W_ih   = (const float*)d_in[3];
    const float* b_ih   = (const float*)d_in[4];
    const float* W_hh   = (const float*)d_in[5];
    const float* b_hh   = (const float*)d_in[6];
    const float* W_ho   = (const float*)d_in[7];
    const float* b_ho   = (const float*)d_in[8];
    float* out = (float*)d_out;

    char* ws = (char*)d_ws;
    u16*   h_all  = (u16*)ws;
    u16*   Whh_bf = (u16*)(ws + WHH_OFF);
    u16*   Who_bf = (u16*)(ws + WHO_OFF);
    float* proj   = (float*)(ws + PROJ_OFF);
    int*   cnt    = (int*)(ws + CNT_OFF);

    prep_kernel<<<5633, 256, 0, stream>>>(W_hh, W_ho, hidden, Whh_bf, Who_bf, h_all, cnt);
    proj_kernel<<<256, 256, 0, stream>>>(emb, W_ih, b_ih, b_hh, proj);
    rnn_seq<<<256, 256, 0, stream>>>(seq, proj, Whh_bf, h_all, cnt);
    out_gemm<<<2048, 256, 0, stream>>>(h_all, Who_bf, b_ho, out);
    hfinal<<<512, 256, 0, stream>>>(h_all, out);
}

// Round 3
// 10597.018 us; speedup vs baseline: 2.9589x; 2.9589x over previous
//
#include <hip/hip_runtime.h>

// ---------------------------------------------------------------------------
// VanillaRNN on MI355X (gfx950)   [R2 = R1 resubmitted after infra flake]
// B=128, S=1024, H=1024, E=512, V=256
//
//  1. prep:   bf16-convert W_hh, W_ho; h_all[:,0,:] = hidden; zero flags
//  2. proj:   proj[v][h] = b_ih[h] + b_hh[h] + dot(emb[v,:], W_ih[h,:])  (fp32)
//  3. rnn_seq: persistent kernel, 8 groups x 32 WGs (group = wg&7 -> XCD),
//             each group owns 16 batch rows; W_hh slice lives in VGPRs;
//             per-step group barrier: distributed release-store flags +
//             single polling wave per WG (relaxed loads + one acquire fence).
//  4. out_gemm: out[b,s,v] = dot(h_all[b,s+1,:], W_ho[v,:]) + b_ho[v]  (MFMA)
//  5. hfinal: d_out tail = fp32(h_all[:,S,:])
// ---------------------------------------------------------------------------

typedef __attribute__((ext_vector_type(8))) short bhalf8;   // 8 bf16 (4 VGPR)
typedef __attribute__((ext_vector_type(4))) float floatx4;  // 4 f32

typedef unsigned short u16;
typedef unsigned int u32;

#define B_  128
#define S_  1024
#define H_  1024
#define E_  512
#define V_  256

// ws layout (bytes)
#define WHH_OFF       (268697600ull)            // 128*1025*1024*2 (h_all)
#define WHO_OFF       (WHH_OFF + 2097152ull)    // 1024*1024*2
#define PROJ_OFF      (WHO_OFF + 524288ull)     // 256*1024*2
#define CNT_OFF       (PROJ_OFF + 1048576ull)   // 256*1024*4
// flags: 8 groups x 32 slots x 16 ints (64B stride) = 4096 ints = 16 KB

#define FLAG_STRIDE   16                        // ints (64 B)
#define NFLAGS        4096

__device__ inline u16 f2bf(float f) {
    u32 u = __builtin_bit_cast(u32, f);
    u32 lsb = (u >> 16) & 1u;
    u += 0x7fffu + lsb;
    return (u16)(u >> 16);
}
__device__ inline float bf2f(u16 h) {
    u32 u = ((u32)h) << 16;
    return __builtin_bit_cast(float, u);
}
__device__ inline bhalf8 ld8(const u16* p) {
    return *(const bhalf8*)p;
}

// ---------------------------------------------------------------------------
// 1. prep
// ---------------------------------------------------------------------------
__global__ __launch_bounds__(256) void prep_kernel(
    const float* __restrict__ W_hh, const float* __restrict__ W_ho,
    const float* __restrict__ hidden,
    u16* __restrict__ Whh_bf, u16* __restrict__ Who_bf,
    u16* __restrict__ h_all, int* __restrict__ cnt)
{
    int i = blockIdx.x * 256 + threadIdx.x;
    if (i < 1048576) {
        Whh_bf[i] = f2bf(W_hh[i]);
    } else if (i < 1048576 + 262144) {
        int j = i - 1048576;
        Who_bf[j] = f2bf(W_ho[j]);
    } else if (i < 1048576 + 262144 + 131072) {
        int j = i - (1048576 + 262144);
        int b = j >> 10, k = j & 1023;
        h_all[(size_t)b * 1025 * 1024 + k] = f2bf(hidden[j]);   // t = 0 row
    } else if (i < 1048576 + 262144 + 131072 + NFLAGS) {
        cnt[i - (1048576 + 262144 + 131072)] = 0;
    }
}

// ---------------------------------------------------------------------------
// 2. proj table: proj[v][h] = b_ih[h] + b_hh[h] + sum_e emb[v][e]*W_ih[h][e]
// ---------------------------------------------------------------------------
__global__ __launch_bounds__(256) void proj_kernel(
    const float* __restrict__ emb, const float* __restrict__ W_ih,
    const float* __restrict__ b_ih, const float* __restrict__ b_hh,
    float* __restrict__ proj)
{
    __shared__ float er[E_];
    int v = blockIdx.x, tid = threadIdx.x;
    er[tid]       = emb[v * E_ + tid];
    er[tid + 256] = emb[v * E_ + 256 + tid];
    __syncthreads();
    const float4* x = (const float4*)er;
    #pragma unroll
    for (int j = 0; j < 4; ++j) {
        int hc = tid + j * 256;
        const float4* w = (const float4*)&W_ih[(size_t)hc * E_];
        float s = 0.f;
        #pragma unroll 8
        for (int e = 0; e < E_ / 4; ++e) {
            float4 ww = w[e]; float4 xx = x[e];
            s += ww.x * xx.x + ww.y * xx.y + ww.z * xx.z + ww.w * xx.w;
        }
        proj[v * H_ + hc] = s + b_ih[hc] + b_hh[hc];
    }
}

// ---------------------------------------------------------------------------
// 3. persistent sequential RNN kernel
//    grid = 256 WGs x 256 threads. group g = wg&7 (XCD-aligned), 32 WGs/group,
//    group owns batch rows [g*16, g*16+16). WG owns 32 h-columns. 4 waves
//    split K=1024 into 256-slices; LDS reduce; tanh; bf16 store.
//    Barrier: leader release-stores t+1 into its 64B-strided flag slot;
//    wave 0 (lanes 0..31) polls the 32 slots with relaxed agent loads +
//    s_sleep backoff, one acquire fence on success; __syncthreads broadcast.
// ---------------------------------------------------------------------------
__global__ __launch_bounds__(256) void rnn_seq(
    const int* __restrict__ seq, const float* __restrict__ proj,
    const u16* __restrict__ Whh, u16* __restrict__ h_all,
    int* __restrict__ cnt)
{
    const int wg = blockIdx.x;
    const int g = wg & 7;
    const int wslot = wg >> 3;          // 0..31 within group
    const int colbase = wslot * 32;
    const int tid = threadIdx.x;
    const int wave = tid >> 6;
    const int lane = tid & 63;
    const int l16 = lane & 15, lq = lane >> 4;
    const int kb = wave * 256;          // wave's K-slice base

    // W_hh slice resident in registers: 2 col-tiles x 8 k-steps
    bhalf8 bfrag[2][8];
    #pragma unroll
    for (int tt = 0; tt < 2; ++tt) {
        #pragma unroll
        for (int ks = 0; ks < 8; ++ks) {
            bfrag[tt][ks] = ld8(&Whh[(size_t)(colbase + tt * 16 + l16) * H_
                                     + kb + ks * 32 + lq * 8]);
        }
    }

    __shared__ float red[4][2][16][17];   // [wave][tile][row][col+pad]

    int* gflags = cnt + g * 32 * FLAG_STRIDE;
    int* myflag = gflags + wslot * FLAG_STRIDE;
    int* pollp  = gflags + (lane & 31) * FLAG_STRIDE;

    const int b0 = g * 16;
    const size_t aRowBase = ((size_t)(b0 + l16) * 1025) * 1024;  // per-lane h row

    // reduce-phase fixed indices
    const int rr = tid & 15;            // batch row within group
    const int cp = tid >> 4;            // 0..15 -> col pair
    const int c0 = 2 * cp, c1 = c0 + 1;
    const size_t hOutBase = ((size_t)(b0 + rr) * 1025) * 1024 + colbase + c0;
    const int seqBase = (b0 + rr) * S_;

    for (int t = 0; t < S_; ++t) {
        // early load (independent of h): token
        int tok = seq[seqBase + t];

        // --- MFMA: z_partial[16 x 32] over this wave's K-slice ---
        const u16* hp = h_all + aRowBase + (size_t)t * 1024 + kb + lq * 8;
        floatx4 acc0 = {0.f, 0.f, 0.f, 0.f};
        floatx4 acc1 = {0.f, 0.f, 0.f, 0.f};
        #pragma unroll
        for (int ks = 0; ks < 8; ++ks) {
            bhalf8 a = ld8(hp + ks * 32);
            acc0 = __builtin_amdgcn_mfma_f32_16x16x32_bf16(a, bfrag[0][ks], acc0, 0, 0, 0);
            acc1 = __builtin_amdgcn_mfma_f32_16x16x32_bf16(a, bfrag[1][ks], acc1, 0, 0, 0);
        }
        float2 pj = *(const float2*)&proj[tok * H_ + colbase + c0];

        #pragma unroll
        for (int j = 0; j < 4; ++j) {    // D layout: row=(lq*4+j), col=l16
            red[wave][0][lq * 4 + j][l16] = acc0[j];
            red[wave][1][lq * 4 + j][l16] = acc1[j];
        }
        __syncthreads();

        // --- reduce 4 waves + x_proj + tanh + bf16 store (2 cols/thread) ---
        float z0 = red[0][c0 >> 4][rr][c0 & 15] + red[1][c0 >> 4][rr][c0 & 15]
                 + red[2][c0 >> 4][rr][c0 & 15] + red[3][c0 >> 4][rr][c0 & 15] + pj.x;
        float z1 = red[0][c1 >> 4][rr][c1 & 15] + red[1][c1 >> 4][rr][c1 & 15]
                 + red[2][c1 >> 4][rr][c1 & 15] + red[3][c1 >> 4][rr][c1 & 15] + pj.y;
        u32 pack = (u32)f2bf(tanhf(z0)) | ((u32)f2bf(tanhf(z1)) << 16);
        *(u32*)&h_all[hOutBase + (size_t)(t + 1) * 1024] = pack;

        // --- group barrier ---
        __syncthreads();                 // drains all waves' h stores (vmcnt 0)
        if (tid == 0)
            __hip_atomic_store(myflag, t + 1, __ATOMIC_RELEASE, __HIP_MEMORY_SCOPE_AGENT);
        if (wave == 0) {
            const int target = t + 1;
            for (;;) {
                int v = __hip_atomic_load(pollp, __ATOMIC_RELAXED, __HIP_MEMORY_SCOPE_AGENT);
                if (__all(v >= target)) break;
                __builtin_amdgcn_s_sleep(1);
            }
            __builtin_amdgcn_fence(__ATOMIC_ACQUIRE, "agent");
        }
        __syncthreads();                 // publish to waves 1..3; doubles as
                                         // pre-LDS-write sync for next iter
    }
}

// ---------------------------------------------------------------------------
// 4. output GEMM: out[b][s][v] = dot(h_all[b][s+1][:], W_ho[v][:]) + b_ho[v]
// ---------------------------------------------------------------------------
__global__ __launch_bounds__(256) void out_gemm(
    const u16* __restrict__ h_all, const u16* __restrict__ Who,
    const float* __restrict__ b_ho, float* __restrict__ out)
{
    const int wg = blockIdx.x;          // 2048 = 128 b x 16 s-tiles
    const int b = wg >> 4;
    const int st = wg & 15;
    const int sbase = st * 64;
    const int tid = threadIdx.x;
    const int wave = tid >> 6;
    const int lane = tid & 63;
    const int l16 = lane & 15, lq = lane >> 4;
    const int vb = wave * 64;

    floatx4 acc[4][4] = {};             // [s-sub][v-sub]
    size_t arow[4];
    #pragma unroll
    for (int ss = 0; ss < 4; ++ss)
        arow[ss] = ((size_t)b * 1025 + sbase + ss * 16 + l16 + 1) * 1024;

    for (int ks = 0; ks < 32; ++ks) {
        const int k = ks * 32 + lq * 8;
        bhalf8 bb[4];
        #pragma unroll
        for (int vt = 0; vt < 4; ++vt)
            bb[vt] = ld8(&Who[(size_t)(vb + vt * 16 + l16) * H_ + k]);
        #pragma unroll
        for (int ss = 0; ss < 4; ++ss) {
            bhalf8 aa = ld8(&h_all[arow[ss] + k]);
            #pragma unroll
            for (int vt = 0; vt < 4; ++vt)
                acc[ss][vt] = __builtin_amdgcn_mfma_f32_16x16x32_bf16(aa, bb[vt], acc[ss][vt], 0, 0, 0);
        }
    }
    #pragma unroll
    for (int ss = 0; ss < 4; ++ss) {
        #pragma unroll
        for (int vt = 0; vt < 4; ++vt) {
            int v = vb + vt * 16 + l16;
            float bias = b_ho[v];
            #pragma unroll
            for (int j = 0; j < 4; ++j) {
                int s = sbase + ss * 16 + lq * 4 + j;
                out[((size_t)b << 18) + (size_t)s * V_ + v] = acc[ss][vt][j] + bias;
            }
        }
    }
}

// ---------------------------------------------------------------------------
// 5. h_final
// ---------------------------------------------------------------------------
__global__ __launch_bounds__(256) void hfinal(const u16* __restrict__ h_all,
                                              float* __restrict__ out)
{
    int i = blockIdx.x * 256 + threadIdx.x;   // 131072
    int b = i >> 10, k = i & 1023;
    out[33554432 + i] = bf2f(h_all[((size_t)b * 1025 + 1024) * 1024 + k]);
}

// ---------------------------------------------------------------------------
extern "C" void kernel_launch(void* const* d_in, const int* in_sizes, int n_in,
                              void* d_out, int out_size, void* d_ws, size_t ws_size,
                              hipStream_t stream) {
    const int*   seq    = (const int*)  d_in[0];
    const float* hidden = (const float*)d_in[1];
    const float* emb    = (const float*)d_in[2];
    const float* W_ih   = (const float*)d_in[3];
    const float* b_ih   = (const float*)d_in[4];
    const float* W_hh   = (const float*)d_in[5];
    const float* b_hh   = (const float*)d_in[6];
    const float* W_ho   = (const float*)d_in[7];
    const float* b_ho   = (const float*)d_in[8];
    float* out = (float*)d_out;

    char* ws = (char*)d_ws;
    u16*   h_all  = (u16*)ws;
    u16*   Whh_bf = (u16*)(ws + WHH_OFF);
    u16*   Who_bf = (u16*)(ws + WHO_OFF);
    float* proj   = (float*)(ws + PROJ_OFF);
    int*   cnt    = (int*)(ws + CNT_OFF);

    prep_kernel<<<5648, 256, 0, stream>>>(W_hh, W_ho, hidden, Whh_bf, Who_bf, h_all, cnt);
    proj_kernel<<<256, 256, 0, stream>>>(emb, W_ih, b_ih, b_hh, proj);
    rnn_seq<<<256, 256, 0, stream>>>(seq, proj, Whh_bf, h_all, cnt);
    out_gemm<<<2048, 256, 0, stream>>>(h_all, Who_bf, b_ho, out);
    hfinal<<<512, 256, 0, stream>>>(h_all, out);
}

// Round 7
// 3871.044 us; speedup vs baseline: 8.1000x; 2.7375x over previous
//
#include <hip/hip_runtime.h>

// ---------------------------------------------------------------------------
// VanillaRNN on MI355X (gfx950)   [R7 = R6 resubmitted; pod flake x3]
// B=128, S=1024, H=1024, E=512, V=256
//
//  1. prep:   bf16-convert W_hh, W_ho; h_all[:,0,:] = hidden; zero flags
//  2. proj:   proj[v][h] = b_ih[h] + b_hh[h] + dot(emb[v,:], W_ih[h,:])  (fp32)
//  3. rnn_seq: persistent kernel, 8 groups x 32 WGs (group = wg&7 -> XCD),
//             group owns 16 batch rows; W_hh slice in VGPRs.
//             Per-step sync: RELAXED agent flag store (write-through, no
//             buffer_wbl2/buffer_inv!) + per-wave poll of its 8 producer
//             WGs' flags, bounded spin (fail-loud, never hang). Same-XCD h
//             visibility via L2: __syncthreads drains vmcnt(0) => h stores
//             acked by shared L2 before flag issues; h[t+1] addresses are
//             always fresh so no stale L1 possible.
//  4. out_gemm: out[b,s,v] = dot(h_all[b,s+1,:], W_ho[v,:]) + b_ho[v]  (MFMA)
//  5. hfinal: d_out tail = fp32(h_all[:,S,:])
// ---------------------------------------------------------------------------

typedef __attribute__((ext_vector_type(8))) short bhalf8;   // 8 bf16 (4 VGPR)
typedef __attribute__((ext_vector_type(4))) float floatx4;  // 4 f32

typedef unsigned short u16;
typedef unsigned int u32;

#define B_  128
#define S_  1024
#define H_  1024
#define E_  512
#define V_  256

// ws layout (bytes)
#define WHH_OFF       (268697600ull)            // 128*1025*1024*2 (h_all)
#define WHO_OFF       (WHH_OFF + 2097152ull)    // 1024*1024*2
#define PROJ_OFF      (WHO_OFF + 524288ull)     // 256*1024*2
#define CNT_OFF       (PROJ_OFF + 1048576ull)   // 256*1024*4
// flags: 8 groups x 32 slots x 16 ints (64B stride) = 4096 ints = 16 KB

#define FLAG_STRIDE   16                        // ints (64 B)
#define NFLAGS        4096
#define SPIN_CAP      16384                     // ~8 ms; fast path hits 1-3

__device__ inline u16 f2bf(float f) {
    u32 u = __builtin_bit_cast(u32, f);
    u32 lsb = (u >> 16) & 1u;
    u += 0x7fffu + lsb;
    return (u16)(u >> 16);
}
__device__ inline float bf2f(u16 h) {
    u32 u = ((u32)h) << 16;
    return __builtin_bit_cast(float, u);
}
__device__ inline bhalf8 ld8(const u16* p) {
    return *(const bhalf8*)p;
}

// ---------------------------------------------------------------------------
// 1. prep
// ---------------------------------------------------------------------------
__global__ __launch_bounds__(256) void prep_kernel(
    const float* __restrict__ W_hh, const float* __restrict__ W_ho,
    const float* __restrict__ hidden,
    u16* __restrict__ Whh_bf, u16* __restrict__ Who_bf,
    u16* __restrict__ h_all, int* __restrict__ cnt)
{
    int i = blockIdx.x * 256 + threadIdx.x;
    if (i < 1048576) {
        Whh_bf[i] = f2bf(W_hh[i]);
    } else if (i < 1048576 + 262144) {
        int j = i - 1048576;
        Who_bf[j] = f2bf(W_ho[j]);
    } else if (i < 1048576 + 262144 + 131072) {
        int j = i - (1048576 + 262144);
        int b = j >> 10, k = j & 1023;
        h_all[(size_t)b * 1025 * 1024 + k] = f2bf(hidden[j]);   // t = 0 row
    } else if (i < 1048576 + 262144 + 131072 + NFLAGS) {
        cnt[i - (1048576 + 262144 + 131072)] = 0;
    }
}

// ---------------------------------------------------------------------------
// 2. proj table: proj[v][h] = b_ih[h] + b_hh[h] + sum_e emb[v][e]*W_ih[h][e]
// ---------------------------------------------------------------------------
__global__ __launch_bounds__(256) void proj_kernel(
    const float* __restrict__ emb, const float* __restrict__ W_ih,
    const float* __restrict__ b_ih, const float* __restrict__ b_hh,
    float* __restrict__ proj)
{
    __shared__ float er[E_];
    int v = blockIdx.x, tid = threadIdx.x;
    er[tid]       = emb[v * E_ + tid];
    er[tid + 256] = emb[v * E_ + 256 + tid];
    __syncthreads();
    const float4* x = (const float4*)er;
    #pragma unroll
    for (int j = 0; j < 4; ++j) {
        int hc = tid + j * 256;
        const float4* w = (const float4*)&W_ih[(size_t)hc * E_];
        float s = 0.f;
        #pragma unroll 8
        for (int e = 0; e < E_ / 4; ++e) {
            float4 ww = w[e]; float4 xx = x[e];
            s += ww.x * xx.x + ww.y * xx.y + ww.z * xx.z + ww.w * xx.w;
        }
        proj[v * H_ + hc] = s + b_ih[hc] + b_hh[hc];
    }
}

// ---------------------------------------------------------------------------
// 3. persistent sequential RNN kernel
//    grid = 256 WGs x 256 threads. group g = wg&7 (XCD-aligned), 32 WGs/group,
//    group owns batch rows [g*16, g*16+16). WG owns 32 h-columns. 4 waves
//    split K=1024 into 256-slices; LDS reduce; tanh; bf16 store.
//    Sync/step: __syncthreads (LDS) ... __syncthreads (drain stores) ->
//    leader RELAXED flag store -> each wave polls its 8 producer flags.
// ---------------------------------------------------------------------------
__global__ __launch_bounds__(256) void rnn_seq(
    const int* __restrict__ seq, const float* __restrict__ proj,
    const u16* __restrict__ Whh, u16* __restrict__ h_all,
    int* __restrict__ cnt)
{
    const int wg = blockIdx.x;
    const int g = wg & 7;
    const int wslot = wg >> 3;          // 0..31 within group
    const int colbase = wslot * 32;
    const int tid = threadIdx.x;
    const int wave = tid >> 6;
    const int lane = tid & 63;
    const int l16 = lane & 15, lq = lane >> 4;
    const int kb = wave * 256;          // wave's K-slice base

    // W_hh slice resident in registers: 2 col-tiles x 8 k-steps
    bhalf8 bfrag[2][8];
    #pragma unroll
    for (int tt = 0; tt < 2; ++tt) {
        #pragma unroll
        for (int ks = 0; ks < 8; ++ks) {
            bfrag[tt][ks] = ld8(&Whh[(size_t)(colbase + tt * 16 + l16) * H_
                                     + kb + ks * 32 + lq * 8]);
        }
    }

    __shared__ float red[4][2][16][17];   // [wave][tile][row][col+pad]

    int* gflags = cnt + g * 32 * FLAG_STRIDE;
    int* myflag = gflags + wslot * FLAG_STRIDE;
    // wave w consumes h cols [w*256, w*256+256) = wslots [w*8, w*8+8)
    int* pollp  = gflags + (wave * 8 + (lane & 7)) * FLAG_STRIDE;

    const int b0 = g * 16;
    const size_t aRowBase = ((size_t)(b0 + l16) * 1025) * 1024;  // per-lane h row

    // reduce-phase fixed indices
    const int rr = tid & 15;            // batch row within group
    const int cp = tid >> 4;            // 0..15 -> col pair
    const int c0 = 2 * cp, c1 = c0 + 1;
    const size_t hOutBase = ((size_t)(b0 + rr) * 1025) * 1024 + colbase + c0;
    const int seqBase = (b0 + rr) * S_;

    for (int t = 0; t < S_; ++t) {
        // early load (independent of h): token
        int tok = seq[seqBase + t];

        // --- MFMA: z_partial[16 x 32] over this wave's K-slice ---
        const u16* hp = h_all + aRowBase + (size_t)t * 1024 + kb + lq * 8;
        floatx4 acc0 = {0.f, 0.f, 0.f, 0.f};
        floatx4 acc1 = {0.f, 0.f, 0.f, 0.f};
        #pragma unroll
        for (int ks = 0; ks < 8; ++ks) {
            bhalf8 a = ld8(hp + ks * 32);
            acc0 = __builtin_amdgcn_mfma_f32_16x16x32_bf16(a, bfrag[0][ks], acc0, 0, 0, 0);
            acc1 = __builtin_amdgcn_mfma_f32_16x16x32_bf16(a, bfrag[1][ks], acc1, 0, 0, 0);
        }
        float2 pj = *(const float2*)&proj[tok * H_ + colbase + c0];

        #pragma unroll
        for (int j = 0; j < 4; ++j) {    // D layout: row=(lq*4+j), col=l16
            red[wave][0][lq * 4 + j][l16] = acc0[j];
            red[wave][1][lq * 4 + j][l16] = acc1[j];
        }
        __syncthreads();

        // --- reduce 4 waves + x_proj + tanh + bf16 store (2 cols/thread) ---
        float z0 = red[0][c0 >> 4][rr][c0 & 15] + red[1][c0 >> 4][rr][c0 & 15]
                 + red[2][c0 >> 4][rr][c0 & 15] + red[3][c0 >> 4][rr][c0 & 15] + pj.x;
        float z1 = red[0][c1 >> 4][rr][c1 & 15] + red[1][c1 >> 4][rr][c1 & 15]
                 + red[2][c1 >> 4][rr][c1 & 15] + red[3][c1 >> 4][rr][c1 & 15] + pj.y;
        u32 pack = (u32)f2bf(tanhf(z0)) | ((u32)f2bf(tanhf(z1)) << 16);
        *(u32*)&h_all[hOutBase + (size_t)(t + 1) * 1024] = pack;

        // --- sync: drains all waves' h stores to L2 (vmcnt 0 before barrier)
        //     and protects `red` for next iteration ---
        __syncthreads();

        // --- publish: RELAXED agent store (write-through; no wbl2/inv) ---
        if (tid == 0)
            __hip_atomic_store(myflag, t + 1, __ATOMIC_RELAXED, __HIP_MEMORY_SCOPE_AGENT);

        // --- per-wave wait on its 8 producer WGs (skip after last step).
        //     Bounded spin: on pathological stall, proceed (=> loud absmax
        //     failure at validation) instead of hanging the container. ---
        if (t < S_ - 1) {
            const int target = t + 1;
            int spins = 0;
            for (;;) {
                int v = (lane < 8)
                    ? __hip_atomic_load(pollp, __ATOMIC_RELAXED, __HIP_MEMORY_SCOPE_AGENT)
                    : 0x7fffffff;
                if (__all(v >= target)) break;
                if (++spins > SPIN_CAP) break;   // safety valve, never hit normally
                __builtin_amdgcn_s_sleep(1);
            }
            asm volatile("" ::: "memory");   // block compiler hoist of h loads
        }
    }
}

// ---------------------------------------------------------------------------
// 4. output GEMM: out[b][s][v] = dot(h_all[b][s+1][:], W_ho[v][:]) + b_ho[v]
// ---------------------------------------------------------------------------
__global__ __launch_bounds__(256) void out_gemm(
    const u16* __restrict__ h_all, const u16* __restrict__ Who,
    const float* __restrict__ b_ho, float* __restrict__ out)
{
    const int wg = blockIdx.x;          // 2048 = 128 b x 16 s-tiles
    const int b = wg >> 4;
    const int st = wg & 15;
    const int sbase = st * 64;
    const int tid = threadIdx.x;
    const int wave = tid >> 6;
    const int lane = tid & 63;
    const int l16 = lane & 15, lq = lane >> 4;
    const int vb = wave * 64;

    floatx4 acc[4][4] = {};             // [s-sub][v-sub]
    size_t arow[4];
    #pragma unroll
    for (int ss = 0; ss < 4; ++ss)
        arow[ss] = ((size_t)b * 1025 + sbase + ss * 16 + l16 + 1) * 1024;

    for (int ks = 0; ks < 32; ++ks) {
        const int k = ks * 32 + lq * 8;
        bhalf8 bb[4];
        #pragma unroll
        for (int vt = 0; vt < 4; ++vt)
            bb[vt] = ld8(&Who[(size_t)(vb + vt * 16 + l16) * H_ + k]);
        #pragma unroll
        for (int ss = 0; ss < 4; ++ss) {
            bhalf8 aa = ld8(&h_all[arow[ss] + k]);
            #pragma unroll
            for (int vt = 0; vt < 4; ++vt)
                acc[ss][vt] = __builtin_amdgcn_mfma_f32_16x16x32_bf16(aa, bb[vt], acc[ss][vt], 0, 0, 0);
        }
    }
    #pragma unroll
    for (int ss = 0; ss < 4; ++ss) {
        #pragma unroll
        for (int vt = 0; vt < 4; ++vt) {
            int v = vb + vt * 16 + l16;
            float bias = b_ho[v];
            #pragma unroll
            for (int j = 0; j < 4; ++j) {
                int s = sbase + ss * 16 + lq * 4 + j;
                out[((size_t)b << 18) + (size_t)s * V_ + v] = acc[ss][vt][j] + bias;
            }
        }
    }
}

// ---------------------------------------------------------------------------
// 5. h_final
// ---------------------------------------------------------------------------
__global__ __launch_bounds__(256) void hfinal(const u16* __restrict__ h_all,
                                              float* __restrict__ out)
{
    int i = blockIdx.x * 256 + threadIdx.x;   // 131072
    int b = i >> 10, k = i & 1023;
    out[33554432 + i] = bf2f(h_all[((size_t)b * 1025 + 1024) * 1024 + k]);
}

// ---------------------------------------------------------------------------
extern "C" void kernel_launch(void* const* d_in, const int* in_sizes, int n_in,
                              void* d_out, int out_size, void* d_ws, size_t ws_size,
                              hipStream_t stream) {
    const int*   seq    = (const int*)  d_in[0];
    const float* hidden = (const float*)d_in[1];
    const float* emb    = (const float*)d_in[2];
    const float* W_ih   = (const float*)d_in[3];
    const float* b_ih   = (const float*)d_in[4];
    const float* W_hh   = (const float*)d_in[5];
    const float* b_hh   = (const float*)d_in[6];
    const float* W_ho   = (const float*)d_in[7];
    const float* b_ho   = (const float*)d_in[8];
    float* out = (float*)d_out;

    char* ws = (char*)d_ws;
    u16*   h_all  = (u16*)ws;
    u16*   Whh_bf = (u16*)(ws + WHH_OFF);
    u16*   Who_bf = (u16*)(ws + WHO_OFF);
    float* proj   = (float*)(ws + PROJ_OFF);
    int*   cnt    = (int*)(ws + CNT_OFF);

    prep_kernel<<<5648, 256, 0, stream>>>(W_hh, W_ho, hidden, Whh_bf, Who_bf, h_all, cnt);
    proj_kernel<<<256, 256, 0, stream>>>(emb, W_ih, b_ih, b_hh, proj);
    rnn_seq<<<256, 256, 0, stream>>>(seq, proj, Whh_bf, h_all, cnt);
    out_gemm<<<2048, 256, 0, stream>>>(h_all, Who_bf, b_ho, out);
    hfinal<<<512, 256, 0, stream>>>(h_all, out);
}